// Round 18
// baseline (423.088 us; speedup 1.0000x reference)
//
#include <hip/hip_runtime.h>
#include <hip/hip_fp16.h>

// Bidirectional char-LSTM + masked max-pool via MFMA:
// GATE-SPLIT (R16) + COMPACT H (R17).
// 256 blocks = 2 dirs x 128 chain-pairs (CH=2), 1024 threads = 16 waves.
// R17 (381us): compact H killed conflicts but 1 block/CU -> 2 waves/SIMD
// left ~60% step time as unhidden latency. R16 proved 16-wave gate-split
// gives 4 waves/SIMD spill-free (weights halve to 12 frags = 48 VGPR/wave)
// but was burned by the duplicated-H overhead (22M conflicts). This round
// combines them: waves 0-7 own gate tiles {i,f}; waves 8-15 own {g,o};
// H stored ONCE: Hc[buf][chain][192] f16, B-frag = broadcast b128 read at
// chain*384 + kt*64 + c4*16 (same-address lanes broadcast; chain 2-way
// aliasing is free). h-writeback single copy (DPP xor2 pair-pack, 4 lanes
// per half0 wave); x-staging 50 lanes of wave 15.
// Per step: half1 computes tanh(g),sig(o) (role-split pairs via DPP xor8,
// 1 trans/lane) -> posts packed f16x2 to exch[256]; half0 computes
// sig(i),sig(f) concurrently; barrier; half0 finishes c/h (+tanh(c)) and
// writes h; half1 writes x(t+1); barrier.

#define TT 512
#define CH 2

typedef _Float16 f16;
typedef _Float16 f16x8 __attribute__((ext_vector_type(8)));
typedef float f32x4 __attribute__((ext_vector_type(4)));
typedef unsigned int u32;
typedef unsigned short u16;

static __device__ __forceinline__ u32 packh2(float lo, float hi) {
    union { struct { f16 x, y; } h; u32 u; } cv;
    cv.h.x = (f16)lo; cv.h.y = (f16)hi;
    return cv.u;
}
static __device__ __forceinline__ float unpk_lo(u32 u) {
    union { u32 u; struct { f16 x, y; } h; } cv; cv.u = u;
    return (float)cv.h.x;
}
static __device__ __forceinline__ float unpk_hi(u32 u) {
    union { u32 u; struct { f16 x, y; } h; } cv; cv.u = u;
    return (float)cv.h.y;
}
static __device__ __forceinline__ float fexp(float x) {
    return __builtin_amdgcn_exp2f(x * 1.44269504088896341f);
}
static __device__ __forceinline__ float frcp(float x) {
    return __builtin_amdgcn_rcpf(x);
}
static __device__ __forceinline__ float sigf(float x) {
    return frcp(1.f + fexp(-x));
}
static __device__ __forceinline__ float xor8(float x) {
    // lane <-> lane^8: DPP row_ror:8 (rotate within rows of 16 == xor 8)
    union { float f; int i; } c; c.f = x;
    c.i = __builtin_amdgcn_mov_dpp(c.i, 0x128, 0xF, 0xF, false);
    return c.f;
}
static __device__ __forceinline__ float xor2(float x) {
    // lane <-> lane^2: quad_perm(2,3,0,1) = 0x4E
    union { float f; int i; } c; c.f = x;
    c.i = __builtin_amdgcn_mov_dpp(c.i, 0x4E, 0xF, 0xF, false);
    return c.f;
}
static __device__ __forceinline__ float sel4(f32x4 v, int q) {
    // q in 0..3, compile-time indices in each arm (no dynamic indexing)
    return (q & 2) ? ((q & 1) ? v[3] : v[2]) : ((q & 1) ? v[1] : v[0]);
}

__global__ __attribute__((amdgpu_flat_work_group_size(1024, 1024),
                          amdgpu_num_vgpr(128)))
void bilstm_gs_compact_kernel(const int* __restrict__ idx,
                              const float* __restrict__ masks,
                              const float* __restrict__ emb,
                              const float* __restrict__ Wih_f, const float* __restrict__ Whh_f,
                              const float* __restrict__ bih_f, const float* __restrict__ bhh_f,
                              const float* __restrict__ Wih_b, const float* __restrict__ Whh_b,
                              const float* __restrict__ bih_b, const float* __restrict__ bhh_b,
                              float* __restrict__ out)
{
    // Hc[buf][chain][k]: k 0..49 = x, 50..63 = 0 pad, 64..191 = h[k-64]
    __shared__ __align__(16) u16 Hc[2][CH][192];   // 1.5 KB
    __shared__ u16 idx16[CH * TT];                 // 2 KB
    __shared__ u32 mbits[TT];                      // 2 KB
    __shared__ u32 exch[CH * 128];                 // 1 KB: (tanh g, sig o)

    const int tid  = threadIdx.x;
    const int lane = tid & 63;
    const int wv   = tid >> 6;        // wave 0..15
    const int half = wv >> 3;         // 0: i/f + state; 1: g/o + x-stage
    const int wvh  = wv & 7;
    const int l15  = lane & 15;
    const int c4   = lane >> 4;       // 0..3 (acc row group / B k-group)
    const int d    = blockIdx.x & 1;  // 0 fwd, 1 bwd
    const int g    = blockIdx.x >> 1; // 0..127
    const int b0   = g * CH;
    const int rev  = d;

    const int chain = l15 & 1;
    const int q     = (l15 >> 1) & 3; // acc row within c4 group
    const int role  = l15 >> 3;       // 0 = A, 1 = B (pair via xor8)

    const float* Wih = d ? Wih_b : Wih_f;
    const float* Whh = d ? Whh_b : Whh_f;
    const float* bih = d ? bih_b : bih_f;
    const float* bhh = d ? bhh_b : bhh_f;

    // ---- init: idx (u16), mask bits, zero Hc (pads stay 0 forever)
    for (int i = tid; i < CH * TT; i += 1024) {
        const int m = i >> 9, t = i & 511;
        idx16[i] = (u16)idx[(b0 + m) * TT + t];
    }
    if (tid < TT) {
        u32 mb = 0;
        for (int m = 0; m < CH; ++m)
            mb |= (masks[(b0 + m) * TT + tid] != 0.f ? 1u : 0u) << m;
        mbits[tid] = mb;
    }
    if (tid < 2 * CH * 192 / 2) {          // 384 u32s
        ((u32*)Hc)[tid] = 0u;
    }

    // ---- W fragments: this wave's 2 gate tiles.
    // half 0: {i: rows [wvh*16,+16)}, {f: rows [128+wvh*16,+16)}
    // half 1: {g: rows [256+wvh*16,+16)}, {o: rows [384+wvh*16,+16)}
    const int tb0 = half * 256 + wvh * 16;
    const int tb1 = tb0 + 128;
    f16x8 w[6][2];
    f32x4 bias4[2];
#pragma unroll
    for (int tt = 0; tt < 2; ++tt) {
        const int n = (tt ? tb1 : tb0) + l15;
        {
            const int nb_ = (tt ? tb1 : tb0) + c4 * 4;
            const float4 bi = *(const float4*)(bih + nb_);
            const float4 bh = *(const float4*)(bhh + nb_);
            bias4[tt][0] = bi.x + bh.x; bias4[tt][1] = bi.y + bh.y;
            bias4[tt][2] = bi.z + bh.z; bias4[tt][3] = bi.w + bh.w;
        }
        // kt = 0: k = c4*8 + j (< 32 < 50) -> Wih (float2 loads)
#pragma unroll
        for (int jj = 0; jj < 4; ++jj) {
            const float2 e = *(const float2*)(Wih + n * 50 + c4 * 8 + jj * 2);
            w[0][tt][2 * jj]     = (f16)e.x;
            w[0][tt][2 * jj + 1] = (f16)e.y;
        }
        // kt = 1: k = 32 + c4*8 + j, real iff k < 50
#pragma unroll
        for (int j = 0; j < 8; ++j) {
            const int k = 32 + c4 * 8 + j;
            float v = 0.f;
            if (k < 50) v = Wih[n * 50 + k];
            w[1][tt][j] = (f16)v;
        }
        // kt = 2..5: k >= 64 -> Whh[n][k-64] (16B aligned float4 x2)
#pragma unroll
        for (int kt = 2; kt < 6; ++kt) {
            const int kh = (kt - 2) * 32 + c4 * 8;
            const float4 e0 = *(const float4*)(Whh + n * 128 + kh);
            const float4 e1 = *(const float4*)(Whh + n * 128 + kh + 4);
            w[kt][tt][0] = (f16)e0.x; w[kt][tt][1] = (f16)e0.y;
            w[kt][tt][2] = (f16)e0.z; w[kt][tt][3] = (f16)e0.w;
            w[kt][tt][4] = (f16)e1.x; w[kt][tt][5] = (f16)e1.y;
            w[kt][tt][6] = (f16)e1.z; w[kt][tt][7] = (f16)e1.w;
        }
    }

    __syncthreads();   // idx16/mbits/Hc-zero visible before x store

    // ---- x staging lanes: wave 15, lanes 0..49 (2 chains x 25 half-pairs)
    const int  tid15 = tid - 960;
    const bool xthr  = (tid15 >= 0) && (tid15 < 50);
    const int  xch   = xthr ? (tid15 / 25) : 0;
    const int  xps   = xthr ? (tid15 % 25) : 0;

    // ---- x for step 0
    if (xthr) {
        const int t0  = rev ? (TT - 1) : 0;
        const int row = idx16[xch * TT + t0];
        const float2 e = *(const float2*)(emb + row * 50 + xps * 2);
        *(u32*)((unsigned char*)&Hc[0][0][0] + xch * 384 + xps * 4) =
            packh2(e.x, e.y);
    }
    __syncthreads();

    float cst = 0.f, rm = -3e38f;

    const int hd = wvh * 16 + c4 * 4 + q;   // this lane's dim
    const int ex = chain * 128 + hd;
    // writeback lanes (half0 only): role 0, even q -> l15 in {0,1,4,5}
    const bool wbthr = (l15 == 0) | (l15 == 1) | (l15 == 4) | (l15 == 5);

    for (int s = 0; s < TT; ++s) {
        const int cur = s & 1;
        const int t   = rev ? (TT - 1 - s) : s;

        // half1/wave15: issue next x load early (consumed after barrier 1)
        float2 e;
        const bool pf = xthr && (s + 1 < TT);
        if (pf) {
            const int t1  = rev ? (TT - 2 - s) : (s + 1);
            const int row = idx16[xch * TT + t1];
            e = *(const float2*)(emb + row * 50 + xps * 2);
        }

        // ---- MFMA: 2 gate tiles x 6 K-steps; B-frag = broadcast b128 read
        const unsigned char* hb =
            (const unsigned char*)&Hc[cur][0][0] + chain * 384;
        f32x4 a0 = bias4[0], a1 = bias4[1];
#pragma unroll
        for (int kt = 0; kt < 6; ++kt) {
            const f16x8 bf = *(const f16x8*)(hb + kt * 64 + c4 * 16);
            a0 = __builtin_amdgcn_mfma_f32_16x16x32_f16(w[kt][0], bf, a0, 0, 0, 0);
            a1 = __builtin_amdgcn_mfma_f32_16x16x32_f16(w[kt][1], bf, a1, 0, 0, 0);
        }
        const float v0 = sel4(a0, q);   // i (half0) / g (half1)
        const float v1 = sel4(a1, q);   // f (half0) / o (half1)

        // ---- role-split nonlinearity (1 trans/lane), DPP pair combine
        const bool rB = (role != 0);
        const float a_in = rB ? v1 : (half ? (v0 + v0) : v0);
        const float sraw = sigf(a_in);
        // A of half1 turns sig(2g) into tanh(g); everyone else keeps sigmoid
        const float sval = (half && !rB) ? (2.f * sraw - 1.f) : sraw;
        const float sx   = xor8(sval);

        if (half) {
            // A: tg=self, so=sx. A posts the packed pair.
            if (!rB) exch[ex] = packh2(sval, sx);
        }
        // half0: si = sig(i), sf = sig(f) for BOTH roles
        const float si = rB ? sx : sval;
        const float sf = rB ? sval : sx;

        __syncthreads();   // barrier 1: exch visible

        unsigned char* nb = (unsigned char*)&Hc[cur ^ 1][0][0];
        if (!half) {
            const u32 ts = exch[ex];
            const float tg = unpk_lo(ts);
            const float so = unpk_hi(ts);
            const float cc = sf * cst + si * tg;
            cst = cc;
            const float th = 2.f * sigf(cc + cc) - 1.f;   // tanh(c)
            const float hh = so * th;
            const float pen = ((mbits[t] >> chain) & 1u) ? 0.f : 1e8f;
            rm = fmaxf(rm, hh - pen);
            // single-copy writeback: dim-pair packed via DPP xor2
            const float hx2 = xor2(hh);                   // h of dim hd^1
            if (wbthr) {
                *(u32*)(nb + chain * 384 + 128 + hd * 2) = packh2(hh, hx2);
            }
        } else if (pf) {
            *(u32*)(nb + xch * 384 + xps * 4) = packh2(e.x, e.y);
        }
        __syncthreads();   // barrier 2: h + x visible for next step
    }

    // ---- output: half0 role-A lanes -> unique (chain, dim)
    if (!half && role == 0) {
        out[(b0 + chain) * 256 + d * 128 + hd] = rm;
    }
}

extern "C" void kernel_launch(void* const* d_in, const int* in_sizes, int n_in,
                              void* d_out, int out_size, void* d_ws, size_t ws_size,
                              hipStream_t stream) {
    const int*   idx   = (const int*)d_in[0];
    const float* masks = (const float*)d_in[1];
    const float* emb   = (const float*)d_in[2];
    const float* Wih_f = (const float*)d_in[3];
    const float* Whh_f = (const float*)d_in[4];
    const float* bih_f = (const float*)d_in[5];
    const float* bhh_f = (const float*)d_in[6];
    const float* Wih_b = (const float*)d_in[7];
    const float* Whh_b = (const float*)d_in[8];
    const float* bih_b = (const float*)d_in[9];
    const float* bhh_b = (const float*)d_in[10];
    float* out = (float*)d_out;

    bilstm_gs_compact_kernel<<<dim3(256), dim3(1024), 0, stream>>>(
        idx, masks, emb,
        Wih_f, Whh_f, bih_f, bhh_f,
        Wih_b, Whh_b, bih_b, bhh_b,
        out);
}